// Round 8
// baseline (2950.664 us; speedup 1.0000x reference)
//
#include <hip/hip_runtime.h>

// EGNN dynamics (alanine dipeptide), fp32, fully fused: one block per batch
// element, entire 4-layer message-passing loop in LDS/registers.
// R1: per-node precompute of edge-GEMV1 halves (42x reuse per node).
// R2: conflict-minimizing edge enum + 4-way partials.
//     BENCH: VGPR=256, 122MB spill writes, occ 12%, VALU 37%, 3581us.
// R5/R6: anti-spill (full unroll on reg arrays, m-loop unroll 2, unroll-1
//     pins, LDS weight vectors).
//     BENCH: spills GONE (WRITE 122MB->288KB, VGPR 224), but 2711us,
//     VALUBusy 17%, occ 12% -> latency-bound on m-loop weight-row loads
//     from global/L2 + 64-bit addr math bloat.
// R7: stage per-layer weight MATRICES in a 32KB LDS buffer (W2^T+CW1 for
//     edge phase; re-staged to NW1 then NW2 for node phases). Row reads
//     become wave-uniform ds_read_b128 broadcasts: ~120cyc LDS latency vs
//     200-300 L2, separate lgkm counter, immediate-offset addressing.

#define NPART   22
#define NDIM    3
#define XDIM    (NPART * NDIM)          // 66
#define H_IN    8
#define HID     64
#define NLAYERS 4
#define EPB     (NPART * (NPART - 1))   // 462 edges per batch
#define BLOCK   256

__device__ __forceinline__ float silu_f(float x) {
    return __fdividef(x, 1.0f + __expf(-x));
}

// acc[0..63] += e0 * w_row[0..63]   (row: 64 contiguous floats)
#define ACC16(ARR, WPTR, E0) do {                                   \
    const float4* _w4 = (const float4*)(WPTR);                      \
    _Pragma("unroll")                                               \
    for (int _q = 0; _q < 16; ++_q) {                               \
        float4 _w = _w4[_q];                                        \
        ARR[4*_q+0] = fmaf((E0), _w.x, ARR[4*_q+0]);                \
        ARR[4*_q+1] = fmaf((E0), _w.y, ARR[4*_q+1]);                \
        ARR[4*_q+2] = fmaf((E0), _w.z, ARR[4*_q+2]);                \
        ARR[4*_q+3] = fmaf((E0), _w.w, ARR[4*_q+3]);                \
    }                                                               \
} while (0)

// acc[0..7] += e0 * w[0..7]
#define ACC8(ARR, WPTR, E0) do {                                    \
    const float4* _w4 = (const float4*)(WPTR);                      \
    float4 _wa = _w4[0], _wb = _w4[1];                              \
    ARR[0] = fmaf((E0), _wa.x, ARR[0]);                             \
    ARR[1] = fmaf((E0), _wa.y, ARR[1]);                             \
    ARR[2] = fmaf((E0), _wa.z, ARR[2]);                             \
    ARR[3] = fmaf((E0), _wa.w, ARR[3]);                             \
    ARR[4] = fmaf((E0), _wb.x, ARR[4]);                             \
    ARR[5] = fmaf((E0), _wb.y, ARR[5]);                             \
    ARR[6] = fmaf((E0), _wb.z, ARR[6]);                             \
    ARR[7] = fmaf((E0), _wb.w, ARR[7]);                             \
} while (0)

__global__ void __launch_bounds__(BLOCK)
w2_transpose_kernel(const float* __restrict__ w2, float* __restrict__ w2t) {
    int l = blockIdx.x;
    for (int i = threadIdx.x; i < HID * HID; i += BLOCK) {
        int k = i >> 6, j = i & 63;
        w2t[l * HID * HID + j * HID + k] = w2[l * HID * HID + k * HID + j];
    }
}

// Edge enumeration: e in [0,462), r = e % 22, c = (r + 1 + e/22) % 22.
// Within a 64-lane wave each r appears <= 3 times -> <=3-way LDS atomic
// serialization (reference ordering was 21-way).
__device__ __forceinline__ void edge_rc(int e, int& r, int& c) {
    int k = e / NPART;
    r = e - k * NPART;
    c = r + 1 + k;
    if (c >= NPART) c -= NPART;
}

// per-layer LDS weight-vector cache offsets
#define WC_RW   0      // W1 row 128 (radial)
#define WC_EA   64     // W1 row 129 (edge_attr)
#define WC_EB2  128    // edge_b2
#define WC_CB1  192    // coord_b1
#define WC_CW2  256    // coord_w2
#define WC_N    320

#define WB_CW1  4096   // cw1 region offset inside wbuf_s (floats)

template <bool TRANSPOSED>
__global__ void __launch_bounds__(BLOCK)
egnn_fused_kernel(const float* __restrict__ t_in,
                  const float* __restrict__ xs,
                  const float* __restrict__ h_init,
                  const float* __restrict__ emb_w,
                  const float* __restrict__ emb_b,
                  const float* __restrict__ edge_w1,
                  const float* __restrict__ edge_b1,
                  const float* __restrict__ edge_w2x,  // transposed (d_ws) or raw
                  const float* __restrict__ edge_b2,
                  const float* __restrict__ node_w1,
                  const float* __restrict__ node_b1,
                  const float* __restrict__ node_w2,
                  const float* __restrict__ node_b2,
                  const float* __restrict__ coord_w1,
                  const float* __restrict__ coord_b1,
                  const float* __restrict__ coord_w2,
                  float*       __restrict__ out) {
    // [feature][node] layout (stride 22): conflict-free gathers.
    __shared__ float h_s   [HID * NPART];
    __shared__ float hagg_s[HID * NPART];
    __shared__ float ns_s  [HID * NPART];
    __shared__ float pr_s  [HID * NPART];   // b1 + h @ W1[0:64]   per node
    __shared__ float pc_s  [HID * NPART];   //      h @ W1[64:128] per node
    __shared__ float wbuf_s[2 * HID * HID]; // 32KB staged weight matrices
    __shared__ float wc_s  [WC_N];          // per-layer weight vectors
    __shared__ float x_s[XDIM], x0_s[XDIM], xacc_s[XDIM];
    __shared__ float ea_s[EPB];
    __shared__ float mean_s[NDIM];

    const int b   = blockIdx.x;
    const int tid = threadIdx.x;
    const float tval = t_in[b];

    // ---- setup: coords, h embedding ----
    if (tid < XDIM) {
        float v = xs[b * XDIM + tid];
        x0_s[tid] = v;
        x_s[tid]  = v;
    }
    for (int idx = tid; idx < NPART * HID; idx += BLOCK) {
        int n = idx >> 6, j = idx & 63;
        float acc = emb_b[j] + tval * emb_w[H_IN * HID + j];
#pragma unroll
        for (int k = 0; k < H_IN; ++k)
            acc = fmaf(h_init[n * H_IN + k], emb_w[k * HID + j], acc);
        h_s[j * NPART + n] = acc;
    }
    __syncthreads();
    for (int e = tid; e < EPB; e += BLOCK) {
        int r, c; edge_rc(e, r, c);
        float dx = x0_s[r*3+0] - x0_s[c*3+0];
        float dy = x0_s[r*3+1] - x0_s[c*3+1];
        float dz = x0_s[r*3+2] - x0_s[c*3+2];
        ea_s[e] = dx*dx + dy*dy + dz*dz;
    }
    __syncthreads();

#pragma unroll 1
    for (int l = 0; l < NLAYERS; ++l) {
        const float* ew1 = edge_w1  + l * (2*HID + 2) * HID;
        const float* eb1 = edge_b1  + l * HID;
        const float* w2x = edge_w2x + l * HID * HID;
        const float* eb2 = edge_b2  + l * HID;
        const float* cw1 = coord_w1 + l * HID * HID;
        const float* cb1 = coord_b1 + l * HID;
        const float* cw2 = coord_w2 + l * HID;
        const float* nw1 = node_w1  + l * 2 * HID * HID;
        const float* nb1 = node_b1  + l * HID;
        const float* nw2 = node_w2  + l * HID * HID;
        const float* nb2 = node_b2  + l * HID;

        // zero aggregators + stage weight vectors + stage W2^T|CW1 matrices
        for (int idx = tid; idx < NPART * HID; idx += BLOCK) hagg_s[idx] = 0.0f;
        if (tid < XDIM) xacc_s[tid] = 0.0f;
        for (int idx = tid; idx < WC_N; idx += BLOCK) {
            int g = idx >> 6, j = idx & 63;
            float v;
            if      (g == 0) v = ew1[(2 * HID) * HID + j];
            else if (g == 1) v = ew1[(2 * HID + 1) * HID + j];
            else if (g == 2) v = eb2[j];
            else if (g == 3) v = cb1[j];
            else             v = cw2[j];
            wc_s[idx] = v;
        }
        if constexpr (TRANSPOSED) {
            // w2x is W2^T ([j][k] contiguous): coalesced float4 copy
            for (int t = tid; t < 1024; t += BLOCK)
                ((float4*)wbuf_s)[t] = ((const float4*)w2x)[t];
        } else {
            // transpose-stage from raw W2 ([k][j]): scalar, L2-cached
            for (int idx = tid; idx < HID * HID; idx += BLOCK) {
                int j = idx >> 6, k = idx & 63;
                wbuf_s[idx] = w2x[k * HID + j];
            }
        }
        for (int t = tid; t < 1024; t += BLOCK)
            ((float4*)(wbuf_s + WB_CW1))[t] = ((const float4*)cw1)[t];

        // ---- per-node precompute of edge-GEMV1 halves (176 threads) ----
        if (tid < NPART * 8) {
            int n = tid >> 3, jg = tid & 7;
            float pr[8], pc[8];
            {
                const float4* b4 = (const float4*)(eb1 + jg * 8);
                float4 wa = b4[0], wb = b4[1];
                pr[0]=wa.x; pr[1]=wa.y; pr[2]=wa.z; pr[3]=wa.w;
                pr[4]=wb.x; pr[5]=wb.y; pr[6]=wb.z; pr[7]=wb.w;
            }
#pragma unroll
            for (int jj = 0; jj < 8; ++jj) pc[jj] = 0.0f;
#pragma unroll 1
            for (int k = 0; k < HID; ++k) {
                float e0 = h_s[k * NPART + n];
                ACC8(pr, ew1 + k * HID + jg * 8, e0);
                ACC8(pc, ew1 + (HID + k) * HID + jg * 8, e0);
            }
#pragma unroll
            for (int jj = 0; jj < 8; ++jj) {
                pr_s[(jg * 8 + jj) * NPART + n] = pr[jj];
                pc_s[(jg * 8 + jj) * NPART + n] = pc[jj];
            }
        }
        __syncthreads();

        // ---- edge phase: one thread per edge ----
#pragma unroll 1
        for (int e = tid; e < EPB; e += BLOCK) {
            int r, c; edge_rc(e, r, c);
            float dx = x_s[r*3+0] - x_s[c*3+0];
            float dy = x_s[r*3+1] - x_s[c*3+1];
            float dz = x_s[r*3+2] - x_s[c*3+2];
            float radial = dx*dx + dy*dy + dz*dz;
            float invn = __fdividef(1.0f, sqrtf(radial) + 1.0f);
            float ux = dx * invn, uy = dy * invn, uz = dz * invn;
            float ea = ea_s[e];

            // a = silu(P_r[r] + P_c[c] + radial*W1rw + ea*W1ea)
            float a[HID];
#pragma unroll
            for (int j = 0; j < HID; ++j) {
                float v = pr_s[j * NPART + r] + pc_s[j * NPART + c];
                v = fmaf(radial, wc_s[WC_RW + j], v);
                v = fmaf(ea,     wc_s[WC_EA + j], v);
                a[j] = silu_f(v);
            }

            float t1[HID];
#pragma unroll
            for (int q = 0; q < 16; ++q) {
                float4 w = ((const float4*)(wc_s + WC_CB1))[q];
                t1[4*q+0] = w.x; t1[4*q+1] = w.y;
                t1[4*q+2] = w.z; t1[4*q+3] = w.w;
            }

            // m_j = silu(a . W2^T[j] + b2[j]); rows from LDS (uniform
            // broadcast ds_read_b128). unroll 2 caps in-flight row temps.
#pragma unroll 2
            for (int j = 0; j < HID; ++j) {
                const float4* w4 = (const float4*)(wbuf_s + j * HID);
                float m0 = wc_s[WC_EB2 + j], m1 = 0.0f, m2 = 0.0f, m3 = 0.0f;
#pragma unroll
                for (int q = 0; q < 4; ++q) {
                    float4 wA = w4[4*q+0], wB = w4[4*q+1];
                    float4 wC = w4[4*q+2], wD = w4[4*q+3];
                    m0 = fmaf(a[16*q+ 0], wA.x, m0);
                    m0 = fmaf(a[16*q+ 1], wA.y, m0);
                    m0 = fmaf(a[16*q+ 2], wA.z, m0);
                    m0 = fmaf(a[16*q+ 3], wA.w, m0);
                    m1 = fmaf(a[16*q+ 4], wB.x, m1);
                    m1 = fmaf(a[16*q+ 5], wB.y, m1);
                    m1 = fmaf(a[16*q+ 6], wB.z, m1);
                    m1 = fmaf(a[16*q+ 7], wB.w, m1);
                    m2 = fmaf(a[16*q+ 8], wC.x, m2);
                    m2 = fmaf(a[16*q+ 9], wC.y, m2);
                    m2 = fmaf(a[16*q+10], wC.z, m2);
                    m2 = fmaf(a[16*q+11], wC.w, m2);
                    m3 = fmaf(a[16*q+12], wD.x, m3);
                    m3 = fmaf(a[16*q+13], wD.y, m3);
                    m3 = fmaf(a[16*q+14], wD.z, m3);
                    m3 = fmaf(a[16*q+15], wD.w, m3);
                }
                float mj = silu_f((m0 + m1) + (m2 + m3));
                atomicAdd(&hagg_s[j * NPART + r], mj);
                ACC16(t1, wbuf_s + WB_CW1 + j * HID, mj);  // LDS CW1 row
            }

            // phi = silu(t1) . cw2
            float phi = 0.0f;
#pragma unroll
            for (int q = 0; q < 16; ++q) {
                float4 w = ((const float4*)(wc_s + WC_CW2))[q];
                phi = fmaf(silu_f(t1[4*q+0]), w.x, phi);
                phi = fmaf(silu_f(t1[4*q+1]), w.y, phi);
                phi = fmaf(silu_f(t1[4*q+2]), w.z, phi);
                phi = fmaf(silu_f(t1[4*q+3]), w.w, phi);
            }
            atomicAdd(&xacc_s[r*3+0], ux * phi);
            atomicAdd(&xacc_s[r*3+1], uy * phi);
            atomicAdd(&xacc_s[r*3+2], uz * phi);
        }
        __syncthreads();

        // ---- restage wbuf <- NW1 (8192 floats) ----
        for (int t = tid; t < 2048; t += BLOCK)
            ((float4*)wbuf_s)[t] = ((const float4*)nw1)[t];
        __syncthreads();

        // ---- node phase 1: 176 threads = 22 nodes x 8 col-groups ----
        if (tid < NPART * 8) {
            int n = tid >> 3, jg = tid & 7;
            float acc[8];
            {
                const float4* b4 = (const float4*)(nb1 + jg * 8);
                float4 wa = b4[0], wb = b4[1];
                acc[0]=wa.x; acc[1]=wa.y; acc[2]=wa.z; acc[3]=wa.w;
                acc[4]=wb.x; acc[5]=wb.y; acc[6]=wb.z; acc[7]=wb.w;
            }
#pragma unroll 1
            for (int k = 0; k < HID; ++k) {
                float e0 = h_s[k * NPART + n];
                ACC8(acc, wbuf_s + k * HID + jg * 8, e0);
            }
#pragma unroll 1
            for (int k = 0; k < HID; ++k) {
                float e0 = hagg_s[k * NPART + n];
                ACC8(acc, wbuf_s + (HID + k) * HID + jg * 8, e0);
            }
#pragma unroll
            for (int jj = 0; jj < 8; ++jj)
                ns_s[(jg * 8 + jj) * NPART + n] = silu_f(acc[jj]);
        }
        __syncthreads();

        // ---- restage wbuf[0:4096] <- NW2 ----
        for (int t = tid; t < 1024; t += BLOCK)
            ((float4*)wbuf_s)[t] = ((const float4*)nw2)[t];
        __syncthreads();

        // ---- node phase 2 + coord residual ----
        if (tid < NPART * 8) {
            int n = tid >> 3, jg = tid & 7;
            float acc[8];
            {
                const float4* b4 = (const float4*)(nb2 + jg * 8);
                float4 wa = b4[0], wb = b4[1];
                acc[0]=wa.x; acc[1]=wa.y; acc[2]=wa.z; acc[3]=wa.w;
                acc[4]=wb.x; acc[5]=wb.y; acc[6]=wb.z; acc[7]=wb.w;
            }
#pragma unroll 1
            for (int k = 0; k < HID; ++k) {
                float e0 = ns_s[k * NPART + n];
                ACC8(acc, wbuf_s + k * HID + jg * 8, e0);
            }
#pragma unroll
            for (int jj = 0; jj < 8; ++jj)
                h_s[(jg * 8 + jj) * NPART + n] += acc[jj];   // residual
        } else if (tid >= NPART * 8 && tid < NPART * 8 + XDIM) {
            int i = tid - NPART * 8;
            x_s[i] += xacc_s[i];                             // coord residual
        }
        __syncthreads();
    }

    // ---- output: vel = (x - x0) minus per-particle-mean ----
    if (tid < XDIM) xacc_s[tid] = x_s[tid] - x0_s[tid];
    __syncthreads();
    if (tid < NDIM) {
        float s = 0.0f;
#pragma unroll
        for (int n = 0; n < NPART; ++n) s += xacc_s[n * NDIM + tid];
        mean_s[tid] = s * (1.0f / NPART);
    }
    __syncthreads();
    if (tid < XDIM) {
        int d = tid - (tid / 3) * 3;
        out[b * XDIM + tid] = xacc_s[tid] - mean_s[d];
    }
}

extern "C" void kernel_launch(void* const* d_in, const int* in_sizes, int n_in,
                              void* d_out, int out_size, void* d_ws, size_t ws_size,
                              hipStream_t stream) {
    const float* t_in    = (const float*)d_in[0];
    const float* xs      = (const float*)d_in[1];
    const float* h_init  = (const float*)d_in[2];
    const float* emb_w   = (const float*)d_in[3];
    const float* emb_b   = (const float*)d_in[4];
    const float* edge_w1 = (const float*)d_in[5];
    const float* edge_b1 = (const float*)d_in[6];
    const float* edge_w2 = (const float*)d_in[7];
    const float* edge_b2 = (const float*)d_in[8];
    const float* node_w1 = (const float*)d_in[9];
    const float* node_b1 = (const float*)d_in[10];
    const float* node_w2 = (const float*)d_in[11];
    const float* node_b2 = (const float*)d_in[12];
    const float* coord_w1= (const float*)d_in[13];
    const float* coord_b1= (const float*)d_in[14];
    const float* coord_w2= (const float*)d_in[15];
    float* out = (float*)d_out;

    const int B = in_sizes[0];                 // 1024
    const size_t w2t_bytes = (size_t)NLAYERS * HID * HID * sizeof(float);

    if (ws_size >= w2t_bytes) {
        float* w2t = (float*)d_ws;
        hipLaunchKernelGGL(w2_transpose_kernel, dim3(NLAYERS), dim3(BLOCK), 0,
                           stream, edge_w2, w2t);
        hipLaunchKernelGGL((egnn_fused_kernel<true>), dim3(B), dim3(BLOCK), 0,
                           stream, t_in, xs, h_init, emb_w, emb_b,
                           edge_w1, edge_b1, w2t, edge_b2,
                           node_w1, node_b1, node_w2, node_b2,
                           coord_w1, coord_b1, coord_w2, out);
    } else {
        hipLaunchKernelGGL((egnn_fused_kernel<false>), dim3(B), dim3(BLOCK), 0,
                           stream, t_in, xs, h_init, emb_w, emb_b,
                           edge_w1, edge_b1, edge_w2, edge_b2,
                           node_w1, node_b1, node_w2, node_b2,
                           coord_w1, coord_b1, coord_w2, out);
    }
}

// Round 9
// 2877.162 us; speedup vs baseline: 1.0255x; 1.0255x over previous
//
#include <hip/hip_runtime.h>

// EGNN dynamics (alanine dipeptide), fp32, fully fused: one block per batch
// element, entire 4-layer message-passing loop in LDS/registers.
// R1: per-node precompute of edge-GEMV1 halves (42x reuse per node).
// R2: conflict-minimizing edge enum + 4-way partials.
//     BENCH: VGPR=256, 122MB spill writes, occ 12%, VALU 37%, 3581us.
// R5/R6: anti-spill (full unroll on reg arrays, m-loop unroll 2, unroll-1
//     pins, LDS weight vectors). BENCH: spills gone (WRITE 288KB, VGPR 224),
//     2711us, VALUBusy 17%, occ 12% -> latency-bound, 2 waves/SIMD.
// R7: staged weight matrices in LDS. BENCH: 2950us (WORSE). Lesson: LDS has
//     no scalar path — wave-uniform weight rows became vector ds_read_b128
//     streams (2048/wave-edge-iter) serializing the LDS pipe. From GLOBAL,
//     uniform rows can scalarize to s_load (SMEM pipe, SGPRs, zero VALU).
// R8: revert to R6 (global weights) + __launch_bounds__(256, 3): force
//     VGPR <= ~170 -> 3 waves/SIMD (12 waves/CU, 3 blocks co-resident).
//     The a[64]+t1[64] live set is 128; the allocator must tighten the ~96
//     temps. Watch WRITE_SIZE for spill regression (falsifier).

#define NPART   22
#define NDIM    3
#define XDIM    (NPART * NDIM)          // 66
#define H_IN    8
#define HID     64
#define NLAYERS 4
#define EPB     (NPART * (NPART - 1))   // 462 edges per batch
#define BLOCK   256

__device__ __forceinline__ float silu_f(float x) {
    // x * sigmoid(x) = x / (1 + exp(-x)); fast HW exp + fast reciprocal.
    return __fdividef(x, 1.0f + __expf(-x));
}

// acc[0..63] += e0 * w_row[0..63]   (row is 64 contiguous floats, wave-uniform)
#define ACC16(ARR, WPTR, E0) do {                                   \
    const float4* _w4 = (const float4*)(WPTR);                      \
    _Pragma("unroll")                                               \
    for (int _q = 0; _q < 16; ++_q) {                               \
        float4 _w = _w4[_q];                                        \
        ARR[4*_q+0] = fmaf((E0), _w.x, ARR[4*_q+0]);                \
        ARR[4*_q+1] = fmaf((E0), _w.y, ARR[4*_q+1]);                \
        ARR[4*_q+2] = fmaf((E0), _w.z, ARR[4*_q+2]);                \
        ARR[4*_q+3] = fmaf((E0), _w.w, ARR[4*_q+3]);                \
    }                                                               \
} while (0)

// acc[0..7] += e0 * w[0..7]
#define ACC8(ARR, WPTR, E0) do {                                    \
    const float4* _w4 = (const float4*)(WPTR);                      \
    float4 _wa = _w4[0], _wb = _w4[1];                              \
    ARR[0] = fmaf((E0), _wa.x, ARR[0]);                             \
    ARR[1] = fmaf((E0), _wa.y, ARR[1]);                             \
    ARR[2] = fmaf((E0), _wa.z, ARR[2]);                             \
    ARR[3] = fmaf((E0), _wa.w, ARR[3]);                             \
    ARR[4] = fmaf((E0), _wb.x, ARR[4]);                             \
    ARR[5] = fmaf((E0), _wb.y, ARR[5]);                             \
    ARR[6] = fmaf((E0), _wb.z, ARR[6]);                             \
    ARR[7] = fmaf((E0), _wb.w, ARR[7]);                             \
} while (0)

__global__ void __launch_bounds__(BLOCK)
w2_transpose_kernel(const float* __restrict__ w2, float* __restrict__ w2t) {
    int l = blockIdx.x;
    for (int i = threadIdx.x; i < HID * HID; i += BLOCK) {
        int k = i >> 6, j = i & 63;
        w2t[l * HID * HID + j * HID + k] = w2[l * HID * HID + k * HID + j];
    }
}

// Edge enumeration: e in [0,462), r = e % 22, c = (r + 1 + e/22) % 22.
// Within a 64-lane wave each r appears <= 3 times -> <=3-way LDS atomic
// serialization (reference ordering was 21-way).
__device__ __forceinline__ void edge_rc(int e, int& r, int& c) {
    int k = e / NPART;
    r = e - k * NPART;
    c = r + 1 + k;
    if (c >= NPART) c -= NPART;
}

// per-layer LDS weight-vector cache offsets
#define WC_RW   0      // W1 row 128 (radial)
#define WC_EA   64     // W1 row 129 (edge_attr)
#define WC_EB2  128    // edge_b2
#define WC_CB1  192    // coord_b1
#define WC_CW2  256    // coord_w2
#define WC_N    320

template <bool TRANSPOSED>
__global__ void __launch_bounds__(BLOCK, 3)
egnn_fused_kernel(const float* __restrict__ t_in,
                  const float* __restrict__ xs,
                  const float* __restrict__ h_init,
                  const float* __restrict__ emb_w,
                  const float* __restrict__ emb_b,
                  const float* __restrict__ edge_w1,
                  const float* __restrict__ edge_b1,
                  const float* __restrict__ edge_w2x,  // transposed (d_ws) or raw
                  const float* __restrict__ edge_b2,
                  const float* __restrict__ node_w1,
                  const float* __restrict__ node_b1,
                  const float* __restrict__ node_w2,
                  const float* __restrict__ node_b2,
                  const float* __restrict__ coord_w1,
                  const float* __restrict__ coord_b1,
                  const float* __restrict__ coord_w2,
                  float*       __restrict__ out) {
    // [feature][node] layout (stride 22): conflict-free gathers.
    __shared__ float h_s   [HID * NPART];
    __shared__ float hagg_s[HID * NPART];
    __shared__ float ns_s  [HID * NPART];
    __shared__ float pr_s  [HID * NPART];   // b1 + h @ W1[0:64]   per node
    __shared__ float pc_s  [HID * NPART];   //      h @ W1[64:128] per node
    __shared__ float wc_s  [WC_N];          // per-layer weight vectors
    __shared__ float x_s[XDIM], x0_s[XDIM], xacc_s[XDIM];
    __shared__ float ea_s[EPB];
    __shared__ float mean_s[NDIM];

    const int b   = blockIdx.x;
    const int tid = threadIdx.x;
    const float tval = t_in[b];

    // ---- setup: coords, h embedding ----
    if (tid < XDIM) {
        float v = xs[b * XDIM + tid];
        x0_s[tid] = v;
        x_s[tid]  = v;
    }
    for (int idx = tid; idx < NPART * HID; idx += BLOCK) {
        int n = idx >> 6, j = idx & 63;
        float acc = emb_b[j] + tval * emb_w[H_IN * HID + j];
#pragma unroll
        for (int k = 0; k < H_IN; ++k)
            acc = fmaf(h_init[n * H_IN + k], emb_w[k * HID + j], acc);
        h_s[j * NPART + n] = acc;
    }
    __syncthreads();
    for (int e = tid; e < EPB; e += BLOCK) {
        int r, c; edge_rc(e, r, c);
        float dx = x0_s[r*3+0] - x0_s[c*3+0];
        float dy = x0_s[r*3+1] - x0_s[c*3+1];
        float dz = x0_s[r*3+2] - x0_s[c*3+2];
        ea_s[e] = dx*dx + dy*dy + dz*dz;
    }
    __syncthreads();

#pragma unroll 1
    for (int l = 0; l < NLAYERS; ++l) {
        const float* ew1 = edge_w1  + l * (2*HID + 2) * HID;
        const float* eb1 = edge_b1  + l * HID;
        const float* w2x = edge_w2x + l * HID * HID;
        const float* eb2 = edge_b2  + l * HID;
        const float* cw1 = coord_w1 + l * HID * HID;
        const float* cb1 = coord_b1 + l * HID;
        const float* cw2 = coord_w2 + l * HID;
        const float* nw1 = node_w1  + l * 2 * HID * HID;
        const float* nb1 = node_b1  + l * HID;
        const float* nw2 = node_w2  + l * HID * HID;
        const float* nb2 = node_b2  + l * HID;

        // zero aggregators + stage per-layer weight vectors into LDS
        for (int idx = tid; idx < NPART * HID; idx += BLOCK) hagg_s[idx] = 0.0f;
        if (tid < XDIM) xacc_s[tid] = 0.0f;
        for (int idx = tid; idx < WC_N; idx += BLOCK) {
            int g = idx >> 6, j = idx & 63;
            float v;
            if      (g == 0) v = ew1[(2 * HID) * HID + j];
            else if (g == 1) v = ew1[(2 * HID + 1) * HID + j];
            else if (g == 2) v = eb2[j];
            else if (g == 3) v = cb1[j];
            else             v = cw2[j];
            wc_s[idx] = v;
        }

        // ---- per-node precompute of edge-GEMV1 halves (176 threads) ----
        if (tid < NPART * 8) {
            int n = tid >> 3, jg = tid & 7;
            float pr[8], pc[8];
            {
                const float4* b4 = (const float4*)(eb1 + jg * 8);
                float4 wa = b4[0], wb = b4[1];
                pr[0]=wa.x; pr[1]=wa.y; pr[2]=wa.z; pr[3]=wa.w;
                pr[4]=wb.x; pr[5]=wb.y; pr[6]=wb.z; pr[7]=wb.w;
            }
#pragma unroll
            for (int jj = 0; jj < 8; ++jj) pc[jj] = 0.0f;
#pragma unroll 1
            for (int k = 0; k < HID; ++k) {
                float e0 = h_s[k * NPART + n];
                ACC8(pr, ew1 + k * HID + jg * 8, e0);
                ACC8(pc, ew1 + (HID + k) * HID + jg * 8, e0);
            }
#pragma unroll
            for (int jj = 0; jj < 8; ++jj) {
                pr_s[(jg * 8 + jj) * NPART + n] = pr[jj];
                pc_s[(jg * 8 + jj) * NPART + n] = pc[jj];
            }
        }
        __syncthreads();

        // ---- edge phase: one thread per edge ----
#pragma unroll 1
        for (int e = tid; e < EPB; e += BLOCK) {
            int r, c; edge_rc(e, r, c);
            float dx = x_s[r*3+0] - x_s[c*3+0];
            float dy = x_s[r*3+1] - x_s[c*3+1];
            float dz = x_s[r*3+2] - x_s[c*3+2];
            float radial = dx*dx + dy*dy + dz*dz;
            float invn = __fdividef(1.0f, sqrtf(radial) + 1.0f);
            float ux = dx * invn, uy = dy * invn, uz = dz * invn;
            float ea = ea_s[e];

            // a = silu(P_r[r] + P_c[c] + radial*W1rw + ea*W1ea)
            float a[HID];
#pragma unroll
            for (int j = 0; j < HID; ++j) {
                float v = pr_s[j * NPART + r] + pc_s[j * NPART + c];
                v = fmaf(radial, wc_s[WC_RW + j], v);
                v = fmaf(ea,     wc_s[WC_EA + j], v);
                a[j] = silu_f(v);
            }

            float t1[HID];
#pragma unroll
            for (int q = 0; q < 16; ++q) {
                float4 w = ((const float4*)(wc_s + WC_CB1))[q];
                t1[4*q+0] = w.x; t1[4*q+1] = w.y;
                t1[4*q+2] = w.z; t1[4*q+3] = w.w;
            }

            // m_j = silu(a . W2^T[j] + b2[j]); rows from GLOBAL (uniform
            // address -> scalar-load path). unroll 2 caps in-flight temps.
#pragma unroll 2
            for (int j = 0; j < HID; ++j) {
                float m0, m1, m2, m3;
                if constexpr (TRANSPOSED) {
                    const float4* w4 = (const float4*)(w2x + j * HID);
                    m0 = wc_s[WC_EB2 + j]; m1 = 0.0f; m2 = 0.0f; m3 = 0.0f;
#pragma unroll
                    for (int q = 0; q < 4; ++q) {
                        float4 wA = w4[4*q+0], wB = w4[4*q+1];
                        float4 wC = w4[4*q+2], wD = w4[4*q+3];
                        m0 = fmaf(a[16*q+ 0], wA.x, m0);
                        m0 = fmaf(a[16*q+ 1], wA.y, m0);
                        m0 = fmaf(a[16*q+ 2], wA.z, m0);
                        m0 = fmaf(a[16*q+ 3], wA.w, m0);
                        m1 = fmaf(a[16*q+ 4], wB.x, m1);
                        m1 = fmaf(a[16*q+ 5], wB.y, m1);
                        m1 = fmaf(a[16*q+ 6], wB.z, m1);
                        m1 = fmaf(a[16*q+ 7], wB.w, m1);
                        m2 = fmaf(a[16*q+ 8], wC.x, m2);
                        m2 = fmaf(a[16*q+ 9], wC.y, m2);
                        m2 = fmaf(a[16*q+10], wC.z, m2);
                        m2 = fmaf(a[16*q+11], wC.w, m2);
                        m3 = fmaf(a[16*q+12], wD.x, m3);
                        m3 = fmaf(a[16*q+13], wD.y, m3);
                        m3 = fmaf(a[16*q+14], wD.z, m3);
                        m3 = fmaf(a[16*q+15], wD.w, m3);
                    }
                } else {
                    m0 = wc_s[WC_EB2 + j]; m1 = 0.0f; m2 = 0.0f; m3 = 0.0f;
#pragma unroll
                    for (int k = 0; k < HID; k += 4) {
                        m0 = fmaf(a[k+0], w2x[(k+0) * HID + j], m0);
                        m1 = fmaf(a[k+1], w2x[(k+1) * HID + j], m1);
                        m2 = fmaf(a[k+2], w2x[(k+2) * HID + j], m2);
                        m3 = fmaf(a[k+3], w2x[(k+3) * HID + j], m3);
                    }
                }
                float mj = silu_f((m0 + m1) + (m2 + m3));
                atomicAdd(&hagg_s[j * NPART + r], mj);
                ACC16(t1, cw1 + j * HID, mj);   // global CW1 row (uniform)
            }

            // phi = silu(t1) . cw2
            float phi = 0.0f;
#pragma unroll
            for (int q = 0; q < 16; ++q) {
                float4 w = ((const float4*)(wc_s + WC_CW2))[q];
                phi = fmaf(silu_f(t1[4*q+0]), w.x, phi);
                phi = fmaf(silu_f(t1[4*q+1]), w.y, phi);
                phi = fmaf(silu_f(t1[4*q+2]), w.z, phi);
                phi = fmaf(silu_f(t1[4*q+3]), w.w, phi);
            }
            atomicAdd(&xacc_s[r*3+0], ux * phi);
            atomicAdd(&xacc_s[r*3+1], uy * phi);
            atomicAdd(&xacc_s[r*3+2], uz * phi);
        }
        __syncthreads();

        // ---- node phase: 176 threads = 22 nodes x 8 col-groups ----
        if (tid < NPART * 8) {
            int n = tid >> 3, jg = tid & 7;
            float acc[8];
            {
                const float4* b4 = (const float4*)(nb1 + jg * 8);
                float4 wa = b4[0], wb = b4[1];
                acc[0]=wa.x; acc[1]=wa.y; acc[2]=wa.z; acc[3]=wa.w;
                acc[4]=wb.x; acc[5]=wb.y; acc[6]=wb.z; acc[7]=wb.w;
            }
#pragma unroll 1
            for (int k = 0; k < HID; ++k) {
                float e0 = h_s[k * NPART + n];
                ACC8(acc, nw1 + k * HID + jg * 8, e0);
            }
#pragma unroll 1
            for (int k = 0; k < HID; ++k) {
                float e0 = hagg_s[k * NPART + n];
                ACC8(acc, nw1 + (HID + k) * HID + jg * 8, e0);
            }
#pragma unroll
            for (int jj = 0; jj < 8; ++jj)
                ns_s[(jg * 8 + jj) * NPART + n] = silu_f(acc[jj]);
        }
        __syncthreads();
        if (tid < NPART * 8) {
            int n = tid >> 3, jg = tid & 7;
            float acc[8];
            {
                const float4* b4 = (const float4*)(nb2 + jg * 8);
                float4 wa = b4[0], wb = b4[1];
                acc[0]=wa.x; acc[1]=wa.y; acc[2]=wa.z; acc[3]=wa.w;
                acc[4]=wb.x; acc[5]=wb.y; acc[6]=wb.z; acc[7]=wb.w;
            }
#pragma unroll 1
            for (int k = 0; k < HID; ++k) {
                float e0 = ns_s[k * NPART + n];
                ACC8(acc, nw2 + k * HID + jg * 8, e0);
            }
#pragma unroll
            for (int jj = 0; jj < 8; ++jj)
                h_s[(jg * 8 + jj) * NPART + n] += acc[jj];   // residual
        } else if (tid >= NPART * 8 && tid < NPART * 8 + XDIM) {
            int i = tid - NPART * 8;
            x_s[i] += xacc_s[i];                             // coord residual
        }
        __syncthreads();
    }

    // ---- output: vel = (x - x0) minus per-particle-mean ----
    if (tid < XDIM) xacc_s[tid] = x_s[tid] - x0_s[tid];
    __syncthreads();
    if (tid < NDIM) {
        float s = 0.0f;
#pragma unroll
        for (int n = 0; n < NPART; ++n) s += xacc_s[n * NDIM + tid];
        mean_s[tid] = s * (1.0f / NPART);
    }
    __syncthreads();
    if (tid < XDIM) {
        int d = tid - (tid / 3) * 3;
        out[b * XDIM + tid] = xacc_s[tid] - mean_s[d];
    }
}

extern "C" void kernel_launch(void* const* d_in, const int* in_sizes, int n_in,
                              void* d_out, int out_size, void* d_ws, size_t ws_size,
                              hipStream_t stream) {
    const float* t_in    = (const float*)d_in[0];
    const float* xs      = (const float*)d_in[1];
    const float* h_init  = (const float*)d_in[2];
    const float* emb_w   = (const float*)d_in[3];
    const float* emb_b   = (const float*)d_in[4];
    const float* edge_w1 = (const float*)d_in[5];
    const float* edge_b1 = (const float*)d_in[6];
    const float* edge_w2 = (const float*)d_in[7];
    const float* edge_b2 = (const float*)d_in[8];
    const float* node_w1 = (const float*)d_in[9];
    const float* node_b1 = (const float*)d_in[10];
    const float* node_w2 = (const float*)d_in[11];
    const float* node_b2 = (const float*)d_in[12];
    const float* coord_w1= (const float*)d_in[13];
    const float* coord_b1= (const float*)d_in[14];
    const float* coord_w2= (const float*)d_in[15];
    float* out = (float*)d_out;

    const int B = in_sizes[0];                 // 1024
    const size_t w2t_bytes = (size_t)NLAYERS * HID * HID * sizeof(float);

    if (ws_size >= w2t_bytes) {
        float* w2t = (float*)d_ws;
        hipLaunchKernelGGL(w2_transpose_kernel, dim3(NLAYERS), dim3(BLOCK), 0,
                           stream, edge_w2, w2t);
        hipLaunchKernelGGL((egnn_fused_kernel<true>), dim3(B), dim3(BLOCK), 0,
                           stream, t_in, xs, h_init, emb_w, emb_b,
                           edge_w1, edge_b1, w2t, edge_b2,
                           node_w1, node_b1, node_w2, node_b2,
                           coord_w1, coord_b1, coord_w2, out);
    } else {
        hipLaunchKernelGGL((egnn_fused_kernel<false>), dim3(B), dim3(BLOCK), 0,
                           stream, t_in, xs, h_init, emb_w, emb_b,
                           edge_w1, edge_b1, edge_w2, edge_b2,
                           node_w1, node_b1, node_w2, node_b2,
                           coord_w1, coord_b1, coord_w2, out);
    }
}

// Round 12
// 2284.946 us; speedup vs baseline: 1.2913x; 1.2592x over previous
//
#include <hip/hip_runtime.h>

// EGNN dynamics (alanine dipeptide), fp32, fully fused, one block per graph.
// History: R2 thread-per-edge: VGPR 256 + 122MB spills, 3581us. R6 anti-spill:
// VGPR 224, latency-bound @2 waves/SIMD, 2711us. R7 LDS weights: 2950us
// (LDS has no scalar path). R8 launch_bounds(256,3) on R6: allocator spilled
// to VGPR 84, 2.08GB scratch traffic, 2877us. Conclusion: a[64]+t1[64]
// per-thread dataflow is structurally stuck (224 VGPR or spill).
// R9 REWRITE of edge phase: wave = edge, lane = feature.
//   - per-lane scalars only; W2 column + CW1 column in 128 regs/lane,
//     loaded once per layer from NATURAL layouts (no transpose kernel).
//   - cross-lane a/m broadcast via per-wave LDS buffers (b128 uniform
//     reads); wave-synchronous, no barriers in edge loop.
//   - phi via 6-step shfl_xor butterfly; hagg atomic 1/lane, stride-23
//     padding -> <=2-way bank aliasing (free), zero atomic contention.
// R11: single delta vs R9: __launch_bounds__ min-waves 3 -> 2. Cap 168 was
//     at/below natural pressure (~170-185 with 128 weight regs); R8 measured
//     that a forced cap wholesale-spills an array (c1r here). Cap 256 is
//     safely above natural -> zero spill risk, 2 waves/SIMD.

#define NPART   22
#define NDIM    3
#define XDIM    (NPART * NDIM)          // 66
#define H_IN    8
#define HID     64
#define NLAYERS 4
#define EPB     (NPART * (NPART - 1))   // 462
#define BLOCK   256
#define NWAVE   4
#define PSTR    23   // padded node stride: odd -> lane-varying j*PSTR reads/
                     // atomics are <=2-way bank aliased (free)

__device__ __forceinline__ float silu_f(float x) {
    return __fdividef(x, 1.0f + __expf(-x));
}

// acc[0..7] += e0 * w[0..7]  (node phase helper)
#define ACC8(ARR, WPTR, E0) do {                                    \
    const float4* _w4 = (const float4*)(WPTR);                      \
    float4 _wa = _w4[0], _wb = _w4[1];                              \
    ARR[0] = fmaf((E0), _wa.x, ARR[0]);                             \
    ARR[1] = fmaf((E0), _wa.y, ARR[1]);                             \
    ARR[2] = fmaf((E0), _wa.z, ARR[2]);                             \
    ARR[3] = fmaf((E0), _wa.w, ARR[3]);                             \
    ARR[4] = fmaf((E0), _wb.x, ARR[4]);                             \
    ARR[5] = fmaf((E0), _wb.y, ARR[5]);                             \
    ARR[6] = fmaf((E0), _wb.z, ARR[6]);                             \
    ARR[7] = fmaf((E0), _wb.w, ARR[7]);                             \
} while (0)

// e in [0,462): r = e % 22, c = (r + 1 + e/22) % 22 (covers all ordered pairs)
__device__ __forceinline__ void edge_rc(int e, int& r, int& c) {
    int k = e / NPART;
    r = e - k * NPART;
    c = r + 1 + k;
    if (c >= NPART) c -= NPART;
}

#define WC_RW 0      // W1 row 128 (radial)
#define WC_EA 64     // W1 row 129 (edge_attr)
#define WC_N  128

__global__ void __launch_bounds__(BLOCK, 2)
egnn_fused_kernel(const float* __restrict__ t_in,
                  const float* __restrict__ xs,
                  const float* __restrict__ h_init,
                  const float* __restrict__ emb_w,
                  const float* __restrict__ emb_b,
                  const float* __restrict__ edge_w1,
                  const float* __restrict__ edge_b1,
                  const float* __restrict__ edge_w2,   // natural [k][j]
                  const float* __restrict__ edge_b2,
                  const float* __restrict__ node_w1,
                  const float* __restrict__ node_b1,
                  const float* __restrict__ node_w2,
                  const float* __restrict__ node_b2,
                  const float* __restrict__ coord_w1,  // natural [j][q]
                  const float* __restrict__ coord_b1,
                  const float* __restrict__ coord_w2,
                  float*       __restrict__ out) {
    __shared__ float h_s   [HID * PSTR];
    __shared__ float hagg_s[HID * PSTR];
    __shared__ float ns_s  [HID * PSTR];
    __shared__ float pr_s  [HID * PSTR];   // b1 + h @ W1[0:64]
    __shared__ float pc_s  [HID * PSTR];   //      h @ W1[64:128]
    __shared__ float wc_s  [WC_N];
    __shared__ __align__(16) float a_s[NWAVE][68];  // per-wave a vector
    __shared__ __align__(16) float m_s[NWAVE][68];  // per-wave m vector
    __shared__ float x_s[XDIM], x0_s[XDIM], xacc_s[XDIM];
    __shared__ float ea_s[EPB];
    __shared__ float mean_s[NDIM];

    const int b    = blockIdx.x;
    const int tid  = threadIdx.x;
    const int w    = tid >> 6;
    const int lane = tid & 63;
    const float tval = t_in[b];

    // ---- setup: coords, h embedding, static edge attr ----
    if (tid < XDIM) {
        float v = xs[b * XDIM + tid];
        x0_s[tid] = v;
        x_s[tid]  = v;
    }
    for (int idx = tid; idx < NPART * HID; idx += BLOCK) {
        int n = idx >> 6, j = idx & 63;
        float acc = emb_b[j] + tval * emb_w[H_IN * HID + j];
#pragma unroll
        for (int k = 0; k < H_IN; ++k)
            acc = fmaf(h_init[n * H_IN + k], emb_w[k * HID + j], acc);
        h_s[j * PSTR + n] = acc;
    }
    __syncthreads();
    for (int e = tid; e < EPB; e += BLOCK) {
        int r, c; edge_rc(e, r, c);
        float dx = x0_s[r*3+0] - x0_s[c*3+0];
        float dy = x0_s[r*3+1] - x0_s[c*3+1];
        float dz = x0_s[r*3+2] - x0_s[c*3+2];
        ea_s[e] = dx*dx + dy*dy + dz*dz;
    }
    __syncthreads();

#pragma unroll 1
    for (int l = 0; l < NLAYERS; ++l) {
        const float* ew1 = edge_w1  + l * (2*HID + 2) * HID;
        const float* eb1 = edge_b1  + l * HID;
        const float* w2l = edge_w2  + l * HID * HID;
        const float* eb2 = edge_b2  + l * HID;
        const float* cw1 = coord_w1 + l * HID * HID;
        const float* cb1 = coord_b1 + l * HID;
        const float* cw2 = coord_w2 + l * HID;
        const float* nw1 = node_w1  + l * 2 * HID * HID;
        const float* nb1 = node_b1  + l * HID;
        const float* nw2 = node_w2  + l * HID * HID;
        const float* nb2 = node_b2  + l * HID;

        // per-layer per-lane weight registers (coalesced, natural layouts):
        // w2r[k] = W2[k][lane]  (column of W2)  — m GEMV operand
        // c1r[j] = CW1[j][lane] (column of CW1) — t1 GEMV operand
        float w2r[HID], c1r[HID];
#pragma unroll
        for (int k = 0; k < HID; ++k) w2r[k] = w2l[k * HID + lane];
#pragma unroll
        for (int k = 0; k < HID; ++k) c1r[k] = cw1[k * HID + lane];
        const float eb2r = eb2[lane];
        const float cb1r = cb1[lane];
        const float cw2r = cw2[lane];

        // zero aggregators + stage W1 tail rows
        for (int idx = tid; idx < HID * PSTR; idx += BLOCK) hagg_s[idx] = 0.0f;
        if (tid < XDIM) xacc_s[tid] = 0.0f;
        if (tid < WC_N) {
            int g = tid >> 6, j = tid & 63;
            wc_s[tid] = ew1[(2 * HID + g) * HID + j];
        }

        // per-node precompute of edge-GEMV1 halves (176 threads)
        if (tid < NPART * 8) {
            int n = tid >> 3, jg = tid & 7;
            float pr[8], pc[8];
            {
                const float4* b4 = (const float4*)(eb1 + jg * 8);
                float4 wa = b4[0], wb = b4[1];
                pr[0]=wa.x; pr[1]=wa.y; pr[2]=wa.z; pr[3]=wa.w;
                pr[4]=wb.x; pr[5]=wb.y; pr[6]=wb.z; pr[7]=wb.w;
            }
#pragma unroll
            for (int jj = 0; jj < 8; ++jj) pc[jj] = 0.0f;
#pragma unroll 1
            for (int k = 0; k < HID; ++k) {
                float e0 = h_s[k * PSTR + n];
                ACC8(pr, ew1 + k * HID + jg * 8, e0);
                ACC8(pc, ew1 + (HID + k) * HID + jg * 8, e0);
            }
#pragma unroll
            for (int jj = 0; jj < 8; ++jj) {
                pr_s[(jg * 8 + jj) * PSTR + n] = pr[jj];
                pc_s[(jg * 8 + jj) * PSTR + n] = pc[jj];
            }
        }
        __syncthreads();

        // ---- edge phase: wave = edge, lane = feature ----
        {
            const int per  = (EPB + NWAVE - 1) / NWAVE;        // 116
            const int ebeg = w * per;
            const int eend = (ebeg + per < EPB) ? (ebeg + per) : EPB;
            float* aw = a_s[w];
            float* mw = m_s[w];
#pragma unroll 1
            for (int e = ebeg; e < eend; ++e) {
                int r, c; edge_rc(e, r, c);                 // wave-uniform
                float dx = x_s[r*3+0] - x_s[c*3+0];
                float dy = x_s[r*3+1] - x_s[c*3+1];
                float dz = x_s[r*3+2] - x_s[c*3+2];
                float radial = dx*dx + dy*dy + dz*dz;
                float invn = __fdividef(1.0f, sqrtf(radial) + 1.0f);
                float ux = dx * invn, uy = dy * invn, uz = dz * invn;
                float ea = ea_s[e];

                // a_j  (j = lane)
                float aj = pr_s[lane * PSTR + r] + pc_s[lane * PSTR + c];
                aj = fmaf(radial, wc_s[WC_RW + lane], aj);
                aj = fmaf(ea,     wc_s[WC_EA + lane], aj);
                aj = silu_f(aj);
                aw[lane] = aj;
                __asm__ volatile("s_waitcnt lgkmcnt(0)" ::: "memory");

                // m_j = silu(eb2_j + a . W2[:,j])  — weights in regs,
                // a via uniform b128 broadcast reads
                float m0 = eb2r, m1 = 0.0f, m2 = 0.0f, m3 = 0.0f;
                const float4* a4 = (const float4*)aw;
#pragma unroll
                for (int q = 0; q < 16; ++q) {
                    float4 av = a4[q];
                    m0 = fmaf(av.x, w2r[4*q+0], m0);
                    m1 = fmaf(av.y, w2r[4*q+1], m1);
                    m2 = fmaf(av.z, w2r[4*q+2], m2);
                    m3 = fmaf(av.w, w2r[4*q+3], m3);
                }
                float mj = silu_f((m0 + m1) + (m2 + m3));
                atomicAdd(&hagg_s[lane * PSTR + r], mj);   // bank-clean
                mw[lane] = mj;
                __asm__ volatile("s_waitcnt lgkmcnt(0)" ::: "memory");

                // t1_q = cb1_q + m . CW1[:,q]
                float t0 = cb1r, t1 = 0.0f, t2 = 0.0f, t3 = 0.0f;
                const float4* m4 = (const float4*)mw;
#pragma unroll
                for (int q = 0; q < 16; ++q) {
                    float4 mv = m4[q];
                    t0 = fmaf(mv.x, c1r[4*q+0], t0);
                    t1 = fmaf(mv.y, c1r[4*q+1], t1);
                    t2 = fmaf(mv.z, c1r[4*q+2], t2);
                    t3 = fmaf(mv.w, c1r[4*q+3], t3);
                }
                float phi = silu_f((t0 + t1) + (t2 + t3)) * cw2r;

                // wave reduction of phi
#pragma unroll
                for (int off = 32; off > 0; off >>= 1)
                    phi += __shfl_xor(phi, off, 64);

                if (lane < NDIM) {
                    float u = (lane == 0) ? ux : ((lane == 1) ? uy : uz);
                    atomicAdd(&xacc_s[r * 3 + lane], u * phi);
                }
            }
        }
        __syncthreads();

        // ---- node phase 1: 176 threads = 22 nodes x 8 col-groups ----
        if (tid < NPART * 8) {
            int n = tid >> 3, jg = tid & 7;
            float acc[8];
            {
                const float4* b4 = (const float4*)(nb1 + jg * 8);
                float4 wa = b4[0], wb = b4[1];
                acc[0]=wa.x; acc[1]=wa.y; acc[2]=wa.z; acc[3]=wa.w;
                acc[4]=wb.x; acc[5]=wb.y; acc[6]=wb.z; acc[7]=wb.w;
            }
#pragma unroll 1
            for (int k = 0; k < HID; ++k) {
                float e0 = h_s[k * PSTR + n];
                ACC8(acc, nw1 + k * HID + jg * 8, e0);
            }
#pragma unroll 1
            for (int k = 0; k < HID; ++k) {
                float e0 = hagg_s[k * PSTR + n];
                ACC8(acc, nw1 + (HID + k) * HID + jg * 8, e0);
            }
#pragma unroll
            for (int jj = 0; jj < 8; ++jj)
                ns_s[(jg * 8 + jj) * PSTR + n] = silu_f(acc[jj]);
        }
        __syncthreads();

        // ---- node phase 2 + coord residual ----
        if (tid < NPART * 8) {
            int n = tid >> 3, jg = tid & 7;
            float acc[8];
            {
                const float4* b4 = (const float4*)(nb2 + jg * 8);
                float4 wa = b4[0], wb = b4[1];
                acc[0]=wa.x; acc[1]=wa.y; acc[2]=wa.z; acc[3]=wa.w;
                acc[4]=wb.x; acc[5]=wb.y; acc[6]=wb.z; acc[7]=wb.w;
            }
#pragma unroll 1
            for (int k = 0; k < HID; ++k) {
                float e0 = ns_s[k * PSTR + n];
                ACC8(acc, nw2 + k * HID + jg * 8, e0);
            }
#pragma unroll
            for (int jj = 0; jj < 8; ++jj)
                h_s[(jg * 8 + jj) * PSTR + n] += acc[jj];   // residual
        } else if (tid >= NPART * 8 && tid < NPART * 8 + XDIM) {
            int i = tid - NPART * 8;
            x_s[i] += xacc_s[i];                            // coord residual
        }
        __syncthreads();
    }

    // ---- output: vel = (x - x0) minus per-particle mean ----
    if (tid < XDIM) xacc_s[tid] = x_s[tid] - x0_s[tid];
    __syncthreads();
    if (tid < NDIM) {
        float s = 0.0f;
#pragma unroll
        for (int n = 0; n < NPART; ++n) s += xacc_s[n * NDIM + tid];
        mean_s[tid] = s * (1.0f / NPART);
    }
    __syncthreads();
    if (tid < XDIM) {
        int d = tid - (tid / 3) * 3;
        out[b * XDIM + tid] = xacc_s[tid] - mean_s[d];
    }
}

extern "C" void kernel_launch(void* const* d_in, const int* in_sizes, int n_in,
                              void* d_out, int out_size, void* d_ws, size_t ws_size,
                              hipStream_t stream) {
    const float* t_in    = (const float*)d_in[0];
    const float* xs      = (const float*)d_in[1];
    const float* h_init  = (const float*)d_in[2];
    const float* emb_w   = (const float*)d_in[3];
    const float* emb_b   = (const float*)d_in[4];
    const float* edge_w1 = (const float*)d_in[5];
    const float* edge_b1 = (const float*)d_in[6];
    const float* edge_w2 = (const float*)d_in[7];
    const float* edge_b2 = (const float*)d_in[8];
    const float* node_w1 = (const float*)d_in[9];
    const float* node_b1 = (const float*)d_in[10];
    const float* node_w2 = (const float*)d_in[11];
    const float* node_b2 = (const float*)d_in[12];
    const float* coord_w1= (const float*)d_in[13];
    const float* coord_b1= (const float*)d_in[14];
    const float* coord_w2= (const float*)d_in[15];
    float* out = (float*)d_out;

    const int B = in_sizes[0];                 // 1024
    (void)d_ws; (void)ws_size;

    hipLaunchKernelGGL(egnn_fused_kernel, dim3(B), dim3(BLOCK), 0, stream,
                       t_in, xs, h_init, emb_w, emb_b,
                       edge_w1, edge_b1, edge_w2, edge_b2,
                       node_w1, node_b1, node_w2, node_b2,
                       coord_w1, coord_b1, coord_w2, out);
}

// Round 13
// 2271.306 us; speedup vs baseline: 1.2991x; 1.0060x over previous
//
#include <hip/hip_runtime.h>

// EGNN dynamics (alanine dipeptide), fp32, fully fused, one block per graph.
// History: R2 thread-per-edge 3581us (spills). R6 anti-spill 2711us
// (latency-bound). R7 LDS weights 2950us (no scalar LDS path). R8 forced
// occupancy 2877us (wholesale spill). R11 wave-per-edge (lane=feature,
// weights-in-regs attempt): 2284us, VGPR 128 (compiler rematerializes
// weight loads from L2 instead of keeping 128 regs), VALUBusy 40%,
// bank-conflicts 3x down. Bottleneck: serial per-edge LDS chain
// (write -> drain -> 16 dependent b128 reads -> ... x2) with ~2 waves/SIMD.
// R12: TWO independent edges (A,B) interleaved per iteration, shared
// drains: {aA,aB write -> drain -> both m-GEMVs (32 indep b128 reads +
// 128 indep FMAs) -> mA,mB write+atomics -> drain -> both t1-GEMVs ->
// 2 interleaved phi butterflies}. Halves drains/edge, doubles ILP at
// every stall point. Per-wave counts (116,116,116,114) even -> no tail.

#define NPART   22
#define NDIM    3
#define XDIM    (NPART * NDIM)          // 66
#define H_IN    8
#define HID     64
#define NLAYERS 4
#define EPB     (NPART * (NPART - 1))   // 462
#define BLOCK   256
#define NWAVE   4
#define PSTR    23   // padded node stride: <=2-way bank aliasing (free)

__device__ __forceinline__ float silu_f(float x) {
    return __fdividef(x, 1.0f + __expf(-x));
}

// acc[0..7] += e0 * w[0..7]  (node phase helper)
#define ACC8(ARR, WPTR, E0) do {                                    \
    const float4* _w4 = (const float4*)(WPTR);                      \
    float4 _wa = _w4[0], _wb = _w4[1];                              \
    ARR[0] = fmaf((E0), _wa.x, ARR[0]);                             \
    ARR[1] = fmaf((E0), _wa.y, ARR[1]);                             \
    ARR[2] = fmaf((E0), _wa.z, ARR[2]);                             \
    ARR[3] = fmaf((E0), _wa.w, ARR[3]);                             \
    ARR[4] = fmaf((E0), _wb.x, ARR[4]);                             \
    ARR[5] = fmaf((E0), _wb.y, ARR[5]);                             \
    ARR[6] = fmaf((E0), _wb.z, ARR[6]);                             \
    ARR[7] = fmaf((E0), _wb.w, ARR[7]);                             \
} while (0)

// e in [0,462): r = e % 22, c = (r + 1 + e/22) % 22 (covers all ordered pairs)
__device__ __forceinline__ void edge_rc(int e, int& r, int& c) {
    int k = e / NPART;
    r = e - k * NPART;
    c = r + 1 + k;
    if (c >= NPART) c -= NPART;
}

#define WC_RW 0      // W1 row 128 (radial)
#define WC_EA 64     // W1 row 129 (edge_attr)
#define WC_N  128

__global__ void __launch_bounds__(BLOCK, 2)
egnn_fused_kernel(const float* __restrict__ t_in,
                  const float* __restrict__ xs,
                  const float* __restrict__ h_init,
                  const float* __restrict__ emb_w,
                  const float* __restrict__ emb_b,
                  const float* __restrict__ edge_w1,
                  const float* __restrict__ edge_b1,
                  const float* __restrict__ edge_w2,   // natural [k][j]
                  const float* __restrict__ edge_b2,
                  const float* __restrict__ node_w1,
                  const float* __restrict__ node_b1,
                  const float* __restrict__ node_w2,
                  const float* __restrict__ node_b2,
                  const float* __restrict__ coord_w1,  // natural [j][q]
                  const float* __restrict__ coord_b1,
                  const float* __restrict__ coord_w2,
                  float*       __restrict__ out) {
    __shared__ float h_s   [HID * PSTR];
    __shared__ float hagg_s[HID * PSTR];
    __shared__ float ns_s  [HID * PSTR];
    __shared__ float pr_s  [HID * PSTR];   // b1 + h @ W1[0:64]
    __shared__ float pc_s  [HID * PSTR];   //      h @ W1[64:128]
    __shared__ float wc_s  [WC_N];
    __shared__ __align__(16) float aA_s[NWAVE][68], aB_s[NWAVE][68];
    __shared__ __align__(16) float mA_s[NWAVE][68], mB_s[NWAVE][68];
    __shared__ float x_s[XDIM], x0_s[XDIM], xacc_s[XDIM];
    __shared__ float ea_s[EPB];
    __shared__ float mean_s[NDIM];

    const int b    = blockIdx.x;
    const int tid  = threadIdx.x;
    const int w    = tid >> 6;
    const int lane = tid & 63;
    const float tval = t_in[b];

    // ---- setup ----
    if (tid < XDIM) {
        float v = xs[b * XDIM + tid];
        x0_s[tid] = v;
        x_s[tid]  = v;
    }
    for (int idx = tid; idx < NPART * HID; idx += BLOCK) {
        int n = idx >> 6, j = idx & 63;
        float acc = emb_b[j] + tval * emb_w[H_IN * HID + j];
#pragma unroll
        for (int k = 0; k < H_IN; ++k)
            acc = fmaf(h_init[n * H_IN + k], emb_w[k * HID + j], acc);
        h_s[j * PSTR + n] = acc;
    }
    __syncthreads();
    for (int e = tid; e < EPB; e += BLOCK) {
        int r, c; edge_rc(e, r, c);
        float dx = x0_s[r*3+0] - x0_s[c*3+0];
        float dy = x0_s[r*3+1] - x0_s[c*3+1];
        float dz = x0_s[r*3+2] - x0_s[c*3+2];
        ea_s[e] = dx*dx + dy*dy + dz*dz;
    }
    __syncthreads();

#pragma unroll 1
    for (int l = 0; l < NLAYERS; ++l) {
        const float* ew1 = edge_w1  + l * (2*HID + 2) * HID;
        const float* eb1 = edge_b1  + l * HID;
        const float* w2l = edge_w2  + l * HID * HID;
        const float* eb2 = edge_b2  + l * HID;
        const float* cw1 = coord_w1 + l * HID * HID;
        const float* cb1 = coord_b1 + l * HID;
        const float* cw2 = coord_w2 + l * HID;
        const float* nw1 = node_w1  + l * 2 * HID * HID;
        const float* nb1 = node_b1  + l * HID;
        const float* nw2 = node_w2  + l * HID * HID;
        const float* nb2 = node_b2  + l * HID;

        // per-lane weight columns (compile-time indices everywhere)
        float w2r[HID], c1r[HID];
#pragma unroll
        for (int k = 0; k < HID; ++k) w2r[k] = w2l[k * HID + lane];
#pragma unroll
        for (int k = 0; k < HID; ++k) c1r[k] = cw1[k * HID + lane];
        const float eb2r = eb2[lane];
        const float cb1r = cb1[lane];
        const float cw2r = cw2[lane];

        for (int idx = tid; idx < HID * PSTR; idx += BLOCK) hagg_s[idx] = 0.0f;
        if (tid < XDIM) xacc_s[tid] = 0.0f;
        if (tid < WC_N) {
            int g = tid >> 6, j = tid & 63;
            wc_s[tid] = ew1[(2 * HID + g) * HID + j];
        }

        // per-node precompute of edge-GEMV1 halves (176 threads)
        if (tid < NPART * 8) {
            int n = tid >> 3, jg = tid & 7;
            float pr[8], pc[8];
            {
                const float4* b4 = (const float4*)(eb1 + jg * 8);
                float4 wa = b4[0], wb = b4[1];
                pr[0]=wa.x; pr[1]=wa.y; pr[2]=wa.z; pr[3]=wa.w;
                pr[4]=wb.x; pr[5]=wb.y; pr[6]=wb.z; pr[7]=wb.w;
            }
#pragma unroll
            for (int jj = 0; jj < 8; ++jj) pc[jj] = 0.0f;
#pragma unroll 1
            for (int k = 0; k < HID; ++k) {
                float e0 = h_s[k * PSTR + n];
                ACC8(pr, ew1 + k * HID + jg * 8, e0);
                ACC8(pc, ew1 + (HID + k) * HID + jg * 8, e0);
            }
#pragma unroll
            for (int jj = 0; jj < 8; ++jj) {
                pr_s[(jg * 8 + jj) * PSTR + n] = pr[jj];
                pc_s[(jg * 8 + jj) * PSTR + n] = pc[jj];
            }
        }
        __syncthreads();

        // ---- edge phase: wave = 2 edges/iter, lane = feature ----
        {
            const int per   = (EPB + NWAVE - 1) / NWAVE;   // 116
            const int ebeg  = w * per;
            const int eend  = (ebeg + per < EPB) ? (ebeg + per) : EPB;
            const int count = eend - ebeg;                 // 116/116/116/114
            const int half  = count >> 1;                  // even counts
            float* awA = aA_s[w]; float* awB = aB_s[w];
            float* mwA = mA_s[w]; float* mwB = mB_s[w];
#pragma unroll 1
            for (int i = 0; i < half; ++i) {
                const int eA = ebeg + i;
                const int eB = ebeg + half + i;
                int rA, cA; edge_rc(eA, rA, cA);
                int rB, cB; edge_rc(eB, rB, cB);
                float dxA = x_s[rA*3+0] - x_s[cA*3+0];
                float dyA = x_s[rA*3+1] - x_s[cA*3+1];
                float dzA = x_s[rA*3+2] - x_s[cA*3+2];
                float dxB = x_s[rB*3+0] - x_s[cB*3+0];
                float dyB = x_s[rB*3+1] - x_s[cB*3+1];
                float dzB = x_s[rB*3+2] - x_s[cB*3+2];
                float radA = dxA*dxA + dyA*dyA + dzA*dzA;
                float radB = dxB*dxB + dyB*dyB + dzB*dzB;
                float invA = __fdividef(1.0f, sqrtf(radA) + 1.0f);
                float invB = __fdividef(1.0f, sqrtf(radB) + 1.0f);
                float uxA = dxA*invA, uyA = dyA*invA, uzA = dzA*invA;
                float uxB = dxB*invB, uyB = dyB*invB, uzB = dzB*invB;
                float eaA = ea_s[eA], eaB = ea_s[eB];

                // a_j for both edges
                float ajA = pr_s[lane * PSTR + rA] + pc_s[lane * PSTR + cA];
                float ajB = pr_s[lane * PSTR + rB] + pc_s[lane * PSTR + cB];
                float wrw = wc_s[WC_RW + lane], wea = wc_s[WC_EA + lane];
                ajA = fmaf(radA, wrw, ajA); ajA = fmaf(eaA, wea, ajA);
                ajB = fmaf(radB, wrw, ajB); ajB = fmaf(eaB, wea, ajB);
                ajA = silu_f(ajA); ajB = silu_f(ajB);
                awA[lane] = ajA;
                awB[lane] = ajB;
                __asm__ volatile("s_waitcnt lgkmcnt(0)" ::: "memory");

                // both m-GEMVs interleaved: 32 indep b128 reads, 128 FMAs
                float mA0 = eb2r, mA1 = 0.0f, mA2 = 0.0f, mA3 = 0.0f;
                float mB0 = eb2r, mB1 = 0.0f, mB2 = 0.0f, mB3 = 0.0f;
                const float4* a4A = (const float4*)awA;
                const float4* a4B = (const float4*)awB;
#pragma unroll
                for (int q = 0; q < 16; ++q) {
                    float4 avA = a4A[q];
                    float4 avB = a4B[q];
                    mA0 = fmaf(avA.x, w2r[4*q+0], mA0);
                    mB0 = fmaf(avB.x, w2r[4*q+0], mB0);
                    mA1 = fmaf(avA.y, w2r[4*q+1], mA1);
                    mB1 = fmaf(avB.y, w2r[4*q+1], mB1);
                    mA2 = fmaf(avA.z, w2r[4*q+2], mA2);
                    mB2 = fmaf(avB.z, w2r[4*q+2], mB2);
                    mA3 = fmaf(avA.w, w2r[4*q+3], mA3);
                    mB3 = fmaf(avB.w, w2r[4*q+3], mB3);
                }
                float mjA = silu_f((mA0 + mA1) + (mA2 + mA3));
                float mjB = silu_f((mB0 + mB1) + (mB2 + mB3));
                atomicAdd(&hagg_s[lane * PSTR + rA], mjA);
                atomicAdd(&hagg_s[lane * PSTR + rB], mjB);
                mwA[lane] = mjA;
                mwB[lane] = mjB;
                __asm__ volatile("s_waitcnt lgkmcnt(0)" ::: "memory");

                // both t1-GEMVs interleaved
                float tA0 = cb1r, tA1 = 0.0f, tA2 = 0.0f, tA3 = 0.0f;
                float tB0 = cb1r, tB1 = 0.0f, tB2 = 0.0f, tB3 = 0.0f;
                const float4* m4A = (const float4*)mwA;
                const float4* m4B = (const float4*)mwB;
#pragma unroll
                for (int q = 0; q < 16; ++q) {
                    float4 mvA = m4A[q];
                    float4 mvB = m4B[q];
                    tA0 = fmaf(mvA.x, c1r[4*q+0], tA0);
                    tB0 = fmaf(mvB.x, c1r[4*q+0], tB0);
                    tA1 = fmaf(mvA.y, c1r[4*q+1], tA1);
                    tB1 = fmaf(mvB.y, c1r[4*q+1], tB1);
                    tA2 = fmaf(mvA.z, c1r[4*q+2], tA2);
                    tB2 = fmaf(mvB.z, c1r[4*q+2], tB2);
                    tA3 = fmaf(mvA.w, c1r[4*q+3], tA3);
                    tB3 = fmaf(mvB.w, c1r[4*q+3], tB3);
                }
                float phiA = silu_f((tA0 + tA1) + (tA2 + tA3)) * cw2r;
                float phiB = silu_f((tB0 + tB1) + (tB2 + tB3)) * cw2r;

                // two interleaved butterflies
#pragma unroll
                for (int off = 32; off > 0; off >>= 1) {
                    phiA += __shfl_xor(phiA, off, 64);
                    phiB += __shfl_xor(phiB, off, 64);
                }

                if (lane < NDIM) {
                    float uA = (lane == 0) ? uxA : ((lane == 1) ? uyA : uzA);
                    float uB = (lane == 0) ? uxB : ((lane == 1) ? uyB : uzB);
                    atomicAdd(&xacc_s[rA * 3 + lane], uA * phiA);
                    atomicAdd(&xacc_s[rB * 3 + lane], uB * phiB);
                }
            }
        }
        __syncthreads();

        // ---- node phase 1: 176 threads = 22 nodes x 8 col-groups ----
        if (tid < NPART * 8) {
            int n = tid >> 3, jg = tid & 7;
            float acc[8];
            {
                const float4* b4 = (const float4*)(nb1 + jg * 8);
                float4 wa = b4[0], wb = b4[1];
                acc[0]=wa.x; acc[1]=wa.y; acc[2]=wa.z; acc[3]=wa.w;
                acc[4]=wb.x; acc[5]=wb.y; acc[6]=wb.z; acc[7]=wb.w;
            }
#pragma unroll 1
            for (int k = 0; k < HID; ++k) {
                float e0 = h_s[k * PSTR + n];
                ACC8(acc, nw1 + k * HID + jg * 8, e0);
            }
#pragma unroll 1
            for (int k = 0; k < HID; ++k) {
                float e0 = hagg_s[k * PSTR + n];
                ACC8(acc, nw1 + (HID + k) * HID + jg * 8, e0);
            }
#pragma unroll
            for (int jj = 0; jj < 8; ++jj)
                ns_s[(jg * 8 + jj) * PSTR + n] = silu_f(acc[jj]);
        }
        __syncthreads();

        // ---- node phase 2 + coord residual ----
        if (tid < NPART * 8) {
            int n = tid >> 3, jg = tid & 7;
            float acc[8];
            {
                const float4* b4 = (const float4*)(nb2 + jg * 8);
                float4 wa = b4[0], wb = b4[1];
                acc[0]=wa.x; acc[1]=wa.y; acc[2]=wa.z; acc[3]=wa.w;
                acc[4]=wb.x; acc[5]=wb.y; acc[6]=wb.z; acc[7]=wb.w;
            }
#pragma unroll 1
            for (int k = 0; k < HID; ++k) {
                float e0 = ns_s[k * PSTR + n];
                ACC8(acc, nw2 + k * HID + jg * 8, e0);
            }
#pragma unroll
            for (int jj = 0; jj < 8; ++jj)
                h_s[(jg * 8 + jj) * PSTR + n] += acc[jj];   // residual
        } else if (tid >= NPART * 8 && tid < NPART * 8 + XDIM) {
            int i = tid - NPART * 8;
            x_s[i] += xacc_s[i];                            // coord residual
        }
        __syncthreads();
    }

    // ---- output: vel = (x - x0) minus per-particle mean ----
    if (tid < XDIM) xacc_s[tid] = x_s[tid] - x0_s[tid];
    __syncthreads();
    if (tid < NDIM) {
        float s = 0.0f;
#pragma unroll
        for (int n = 0; n < NPART; ++n) s += xacc_s[n * NDIM + tid];
        mean_s[tid] = s * (1.0f / NPART);
    }
    __syncthreads();
    if (tid < XDIM) {
        int d = tid - (tid / 3) * 3;
        out[b * XDIM + tid] = xacc_s[tid] - mean_s[d];
    }
}

extern "C" void kernel_launch(void* const* d_in, const int* in_sizes, int n_in,
                              void* d_out, int out_size, void* d_ws, size_t ws_size,
                              hipStream_t stream) {
    const float* t_in    = (const float*)d_in[0];
    const float* xs      = (const float*)d_in[1];
    const float* h_init  = (const float*)d_in[2];
    const float* emb_w   = (const float*)d_in[3];
    const float* emb_b   = (const float*)d_in[4];
    const float* edge_w1 = (const float*)d_in[5];
    const float* edge_b1 = (const float*)d_in[6];
    const float* edge_w2 = (const float*)d_in[7];
    const float* edge_b2 = (const float*)d_in[8];
    const float* node_w1 = (const float*)d_in[9];
    const float* node_b1 = (const float*)d_in[10];
    const float* node_w2 = (const float*)d_in[11];
    const float* node_b2 = (const float*)d_in[12];
    const float* coord_w1= (const float*)d_in[13];
    const float* coord_b1= (const float*)d_in[14];
    const float* coord_w2= (const float*)d_in[15];
    float* out = (float*)d_out;

    const int B = in_sizes[0];                 // 1024
    (void)d_ws; (void)ws_size;

    hipLaunchKernelGGL(egnn_fused_kernel, dim3(B), dim3(BLOCK), 0, stream,
                       t_in, xs, h_init, emb_w, emb_b,
                       edge_w1, edge_b1, edge_w2, edge_b2,
                       node_w1, node_b1, node_w2, node_b2,
                       coord_w1, coord_b1, coord_w2, out);
}